// Round 14
// baseline (131.224 us; speedup 1.0000x reference)
//
#include <hip/hip_runtime.h>
#include <math.h>

// fp16-MFMA flash attention (no-max softmax), S=8192, D=128, fp32 in/out.
// R14: 16 k-slices with FP16 partial-O buffers (32 MB, not R9's 64 MB fp32),
// grid 1024 = 4 blocks/CU, launch_bounds(256,4) -> 4 waves/SIMD latency
// hiding. 32-key dbuf (32 KB LDS/block so 4 blocks fit). Core unchanged:
// transposed-S fp16 QK^T (A=K,B=Q), dual-S accumulators, in-register P
// transpose via shfl_xor(32), async global_load_lds staging.
// Graveyard: R8/R11 fusion (fences/coop), R9 fp32 16-slice (write flood),
// R10 direct L2->reg, R13 source pipelining (compiler already does it).

typedef _Float16 f16x8 __attribute__((ext_vector_type(8)));
typedef float    f32x16 __attribute__((ext_vector_type(16)));

constexpr int S_LEN = 8192;
constexpr int D_K   = 128;

// ws: Lpart[16][8192] fp32 (512 KB) | KV frags (4 MB) | fp16 Opart[16] x 2 MB
constexpr size_t WS_L_OFF = 0;
constexpr size_t KV_OFF   = 524288;
constexpr size_t PART_OFF = KV_OFF + (size_t)256 * 16384;            // 4.5 MB
constexpr size_t WS_NEED  = PART_OFF + (size_t)16 * S_LEN * 64 * 4;  // ~38.5 MB

#define CSCALE (0.08838834764831845f * 1.44269504088896340736f)

union UH8 { _Float16 h[8]; uint4 q; f16x8 v; };
union UF4 { unsigned u[4]; uint4 q; f16x8 v; };
union UHP { unsigned u; _Float16 h[2]; };

__device__ inline void async16(const uint4* g, uint4* l) {
  __builtin_amdgcn_global_load_lds(
      (const __attribute__((address_space(1))) unsigned int*)g,
      (__attribute__((address_space(3))) unsigned int*)l, 16, 0, 0);
}

// ---------------- prep: frag build (+ zero out/ws_l if atomic path) ----------
template <bool ZOUT>
__global__ __launch_bounds__(512) void attn_prep(const float* __restrict__ K,
                                                 const float* __restrict__ V,
                                                 float* __restrict__ out,
                                                 char* __restrict__ ws) {
  const int t = blockIdx.x * 512 + threadIdx.x;
  uint4* KVg = (uint4*)(ws + KV_OFF);
  if (t < 131072) {
    // K frag: lane holds K[key=lane&31][d0..d0+7], d0 = s*16 + (lane>>5)*8
    int kt = t >> 9, idx = t & 511;
    int lane = idx & 63, s = idx >> 6;
    int key = kt * 32 + (lane & 31);
    int d0  = s * 16 + (lane >> 5) * 8;
    const float4* src = (const float4*)(K + (size_t)key * D_K + d0);
    float4 a = src[0], b = src[1];
    float f[8] = {a.x, a.y, a.z, a.w, b.x, b.y, b.z, b.w};
    UH8 h;
    #pragma unroll
    for (int j = 0; j < 8; ++j) h.h[j] = (_Float16)f[j];
    KVg[(size_t)kt * 1024 + idx] = h.q;
  } else if (t < 262144) {
    // V frag: lane holds V[kb..kb+7][d], d = c*32 + (lane&31)
    int g = t - 131072;
    int kt = g >> 9, idx = g & 511;
    int lane = idx & 63, c = (idx >> 6) & 3, kstep = idx >> 8;
    int d  = c * 32 + (lane & 31);
    int kb = kt * 32 + kstep * 16 + (lane >> 5) * 8;
    UH8 h;
    #pragma unroll
    for (int j = 0; j < 8; ++j) h.h[j] = (_Float16)V[(size_t)(kb + j) * D_K + d];
    KVg[(size_t)kt * 1024 + 512 + idx] = h.q;
  } else if (ZOUT && t < 327680) {
    int i = t - 262144;  // zero out
    float4 z = make_float4(0.f, 0.f, 0.f, 0.f);
    float4* o4 = (float4*)out;
    #pragma unroll
    for (int j = 0; j < 4; ++j) o4[(size_t)i * 4 + j] = z;
  } else if (ZOUT && t < 329728) {
    int i = t - 327680;  // zero ws_l (first 8192 floats)
    ((float4*)(ws + WS_L_OFF))[i] = make_float4(0.f, 0.f, 0.f, 0.f);
  }
}

// ---------------- main attention kernel ----------------
// PARTIAL: 16 slices, fp16 partial stores, grid 1024, 4 waves/SIMD.
// !PARTIAL: 8 slices, fp32 atomics into out, grid 512 (fallback).
template <bool PARTIAL>
__global__ __launch_bounds__(256, PARTIAL ? 4 : 2)
void attn_main(const float* __restrict__ Qg, float* __restrict__ out,
               char* __restrict__ ws) {
  constexpr int NSL   = PARTIAL ? 16 : 8;
  constexpr int ITERS = (S_LEN / NSL) / 32;

  __shared__ uint4 KV[2][1024];   // 32-key dbuf: [K 512 | V 512]

  const int tid   = threadIdx.x;
  const int wave  = tid >> 6;
  const int lane  = tid & 63;
  const int lrow  = lane & 31;
  const int lhalf = lane >> 5;

  const int blk = blockIdx.x;
  const int ks  = blk & (NSL - 1);       // k-slice; XCD = blk&7
  const int qb  = blk / NSL;
  const int qw  = qb * 128 + wave * 32;  // wave's 32-row q base

  float* ws_l = (float*)(ws + WS_L_OFF);

  // ---- Q B-frags: lane holds Q[q=lane&31][d=(lane>>5)*8+j + 16s], scaled ----
  f16x8 qf[8];
  {
    const int q = qw + lrow;
    #pragma unroll
    for (int s = 0; s < 8; ++s) {
      const float4* src = (const float4*)(Qg + (size_t)q * D_K + s * 16 + lhalf * 8);
      float4 a = src[0], b = src[1];
      float f[8] = {a.x, a.y, a.z, a.w, b.x, b.y, b.z, b.w};
      UH8 h;
      #pragma unroll
      for (int j = 0; j < 8; ++j) h.h[j] = (_Float16)(f[j] * CSCALE);
      qf[s] = h.v;
    }
  }

  f32x16 O0{}, O1{}, O2{}, O3{};
  float lsum = 0.f;

  const uint4* KVg = (const uint4*)(ws + KV_OFF);

  // prologue: stage tile 0
  {
    const size_t base = (size_t)(ks * ITERS) * 1024;
    #pragma unroll
    for (int i = 0; i < 4; ++i)
      async16(KVg + base + i * 256 + tid, &KV[0][i * 256 + tid]);
  }

  for (int it = 0; it < ITERS; ++it) {
    const int buf = it & 1;
    __syncthreads();   // drains async loads -> KV[buf] ready

    if (it + 1 < ITERS) {
      const size_t base = (size_t)(ks * ITERS + it + 1) * 1024;
      #pragma unroll
      for (int i = 0; i < 4; ++i)
        async16(KVg + base + i * 256 + tid, &KV[buf ^ 1][i * 256 + tid]);
    }

    // ---- S^T = K Q^T : dual accumulators ----
    f32x16 Sa{}, Sb{};
    #pragma unroll
    for (int s = 0; s < 4; ++s) {
      f16x8 ka = __builtin_bit_cast(f16x8, KV[buf][(2 * s    ) * 64 + lane]);
      f16x8 kb = __builtin_bit_cast(f16x8, KV[buf][(2 * s + 1) * 64 + lane]);
      Sa = __builtin_amdgcn_mfma_f32_32x32x16_f16(ka, qf[2 * s    ], Sa, 0, 0, 0);
      Sb = __builtin_amdgcn_mfma_f32_32x32x16_f16(kb, qf[2 * s + 1], Sb, 0, 0, 0);
    }

    // ---- P^T = exp2(Sa+Sb); row sums; pack fp16 pairs ----
    unsigned pk[8];
    #pragma unroll
    for (int i = 0; i < 8; ++i) {
      float p0 = __builtin_amdgcn_exp2f(Sa[2 * i]     + Sb[2 * i]);
      float p1 = __builtin_amdgcn_exp2f(Sa[2 * i + 1] + Sb[2 * i + 1]);
      lsum += p0 + p1;
      pk[i] = __builtin_bit_cast(unsigned, __builtin_amdgcn_cvt_pkrtz(p0, p1));
    }

    // ---- in-register transpose to P A-frags (lane<->lane+32 half swap) ----
    unsigned s0 = __shfl_xor(pk[0], 32), s1 = __shfl_xor(pk[1], 32);
    unsigned s2 = __shfl_xor(pk[2], 32), s3 = __shfl_xor(pk[3], 32);
    unsigned s4 = __shfl_xor(pk[4], 32), s5 = __shfl_xor(pk[5], 32);
    unsigned s6 = __shfl_xor(pk[6], 32), s7 = __shfl_xor(pk[7], 32);
    UF4 A0, A1;
    A0.u[0] = lhalf ? s2 : pk[0];
    A0.u[1] = lhalf ? s3 : pk[1];
    A0.u[2] = lhalf ? pk[2] : s0;
    A0.u[3] = lhalf ? pk[3] : s1;
    A1.u[0] = lhalf ? s6 : pk[4];
    A1.u[1] = lhalf ? s7 : pk[5];
    A1.u[2] = lhalf ? pk[6] : s4;
    A1.u[3] = lhalf ? pk[7] : s5;

    // ---- O += P V : 8 MFMAs, 4 independent chains ----
    #pragma unroll
    for (int kstep = 0; kstep < 2; ++kstep) {
      f16x8 pf = kstep ? A1.v : A0.v;
      f16x8 v0 = __builtin_bit_cast(f16x8, KV[buf][512 + kstep * 256 +   0 + lane]);
      f16x8 v1 = __builtin_bit_cast(f16x8, KV[buf][512 + kstep * 256 +  64 + lane]);
      f16x8 v2 = __builtin_bit_cast(f16x8, KV[buf][512 + kstep * 256 + 128 + lane]);
      f16x8 v3 = __builtin_bit_cast(f16x8, KV[buf][512 + kstep * 256 + 192 + lane]);
      O0 = __builtin_amdgcn_mfma_f32_32x32x16_f16(pf, v0, O0, 0, 0, 0);
      O1 = __builtin_amdgcn_mfma_f32_32x32x16_f16(pf, v1, O1, 0, 0, 0);
      O2 = __builtin_amdgcn_mfma_f32_32x32x16_f16(pf, v2, O2, 0, 0, 0);
      O3 = __builtin_amdgcn_mfma_f32_32x32x16_f16(pf, v3, O3, 0, 0, 0);
    }
  }

  // ---- epilogue ----
  lsum += __shfl_xor(lsum, 32);           // combine the two key-halves

  if (PARTIAL) {
    if (lhalf == 0) ws_l[ks * S_LEN + qw + lrow] = lsum;   // plain store
    // fp16 partial O, packed layout: row of 64 uints; col c holds (d=c, d=c+64)
    unsigned* obase = (unsigned*)(ws + PART_OFF)
                    + (size_t)ks * S_LEN * 64 + (size_t)qw * 64;
    #pragma unroll
    for (int r = 0; r < 16; ++r) {
      int row = (r & 3) + 8 * (r >> 2) + 4 * lhalf;
      unsigned p02 = __builtin_bit_cast(unsigned, __builtin_amdgcn_cvt_pkrtz(O0[r], O2[r]));
      unsigned p13 = __builtin_bit_cast(unsigned, __builtin_amdgcn_cvt_pkrtz(O1[r], O3[r]));
      obase[(size_t)row * 64 + lrow]      = p02;   // d = lrow,    lrow+64
      obase[(size_t)row * 64 + 32 + lrow] = p13;   // d = lrow+32, lrow+96
    }
  } else {
    if (lhalf == 0) atomicAdd(ws_l + qw + lrow, lsum);
    #pragma unroll
    for (int r = 0; r < 16; ++r) {
      int row = (r & 3) + 8 * (r >> 2) + 4 * lhalf;
      float* dst = out + (size_t)(qw + row) * D_K + lrow;
      atomicAdd(dst +  0, O0[r]);
      atomicAdd(dst + 32, O1[r]);
      atomicAdd(dst + 64, O2[r]);
      atomicAdd(dst + 96, O3[r]);
    }
  }
}

// ---------------- reduce 16 fp16 partials + normalize ----------------
__global__ __launch_bounds__(256) void attn_norm16(float* __restrict__ out,
                                                   const float* __restrict__ lpart,
                                                   const unsigned* __restrict__ opart) {
  int t = blockIdx.x * 256 + threadIdx.x;   // 131072 threads
  int q  = t >> 4;
  int cg = t & 15;                          // col group: cols 4cg..4cg+3

  float l = 0.f;
  #pragma unroll
  for (int s = 0; s < 16; ++s) l += lpart[s * S_LEN + q];
  float inv = 1.0f / l;

  float acc[8] = {0.f, 0.f, 0.f, 0.f, 0.f, 0.f, 0.f, 0.f};
  #pragma unroll
  for (int s = 0; s < 16; ++s) {
    const uint4* src = (const uint4*)(opart + (size_t)s * S_LEN * 64
                                      + (size_t)q * 64 + 4 * cg);
    uint4 u = src[0];
    UHP a, b, c, d;
    a.u = u.x; b.u = u.y; c.u = u.z; d.u = u.w;
    acc[0] += (float)a.h[0]; acc[4] += (float)a.h[1];
    acc[1] += (float)b.h[0]; acc[5] += (float)b.h[1];
    acc[2] += (float)c.h[0]; acc[6] += (float)c.h[1];
    acc[3] += (float)d.h[0]; acc[7] += (float)d.h[1];
  }
  float4* o4 = (float4*)out;
  o4[(size_t)q * 32 + cg] =
      make_float4(acc[0] * inv, acc[1] * inv, acc[2] * inv, acc[3] * inv);
  o4[(size_t)q * 32 + 16 + cg] =
      make_float4(acc[4] * inv, acc[5] * inv, acc[6] * inv, acc[7] * inv);
}

// ---------------- normalize only (atomic fallback) ----------------
__global__ __launch_bounds__(256) void attn_norm_fb(float* __restrict__ out,
                                                    const float* __restrict__ ws_l) {
  int i = blockIdx.x * 256 + threadIdx.x;
  float4* o4 = (float4*)out;
  float4 o = o4[i];
  float inv = 1.0f / ws_l[i >> 5];
  o.x *= inv; o.y *= inv; o.z *= inv; o.w *= inv;
  o4[i] = o;
}

extern "C" void kernel_launch(void* const* d_in, const int* in_sizes, int n_in,
                              void* d_out, int out_size, void* d_ws, size_t ws_size,
                              hipStream_t stream) {
  const float* q = (const float*)d_in[0];
  const float* k = (const float*)d_in[1];
  const float* v = (const float*)d_in[2];
  float* out = (float*)d_out;
  char* ws = (char*)d_ws;

  if (ws_size >= WS_NEED) {
    attn_prep<false><<<dim3(512), dim3(512), 0, stream>>>(k, v, out, ws);
    attn_main<true><<<dim3(1024), dim3(256), 0, stream>>>(q, out, ws);
    attn_norm16<<<dim3(512), dim3(256), 0, stream>>>(
        out, (const float*)(ws + WS_L_OFF), (const unsigned*)(ws + PART_OFF));
  } else {
    attn_prep<true><<<dim3(645), dim3(512), 0, stream>>>(k, v, out, ws);
    attn_main<false><<<dim3(512), dim3(256), 0, stream>>>(q, out, ws);
    attn_norm_fb<<<dim3(1024), dim3(256), 0, stream>>>(
        out, (const float*)(ws + WS_L_OFF));
  }
}

// Round 15
// 116.688 us; speedup vs baseline: 1.1246x; 1.1246x over previous
//
#include <hip/hip_runtime.h>
#include <math.h>

// fp16-MFMA flash attention (no-max softmax), S=8192, D=128, fp32 in/out.
// R15: 64 q-rows per wave (2 tiles) so every K/V LDS frag read feeds 2 MFMAs
// -- halves the LDS-pipe load that bound R12 at 49 us (measured: 98K cyc/CU
// of ds_read_b128 == the whole kernel). 16 slices + fp16 partials (R14-style,
// numerically free) keep 2 waves/SIMD at the doubled q-per-wave. Grid 512,
// launch_bounds(256,2), ~250 VGPR budget: O 128 + Q 64 + S 32 + transients.
// Core: transposed-S fp16 QK^T (A=K,B=Q), in-register P transpose via
// shfl_xor(32), async global_load_lds 32-key dbuf.
// Graveyard: R8/R11 fusion, R9 fp32 16-slice, R10 direct L2->reg, R13 source
// pipelining, R14 16-slice at 32q/wave (LDS load unchanged -> overhead only).

typedef _Float16 f16x8 __attribute__((ext_vector_type(8)));
typedef float    f32x16 __attribute__((ext_vector_type(16)));

constexpr int S_LEN = 8192;
constexpr int D_K   = 128;

// ws: Lpart[16][8192] fp32 (512 KB) | KV frags (4 MB) | fp16 Opart[16] x 2 MB
constexpr size_t WS_L_OFF = 0;
constexpr size_t KV_OFF   = 524288;
constexpr size_t PART_OFF = KV_OFF + (size_t)256 * 16384;            // 4.5 MB
constexpr size_t WS_NEED  = PART_OFF + (size_t)16 * S_LEN * 64 * 4;  // ~38.5 MB

#define CSCALE (0.08838834764831845f * 1.44269504088896340736f)

union UH8 { _Float16 h[8]; uint4 q; f16x8 v; };
union UF4 { unsigned u[4]; uint4 q; f16x8 v; };
union UHP { unsigned u; _Float16 h[2]; };

__device__ inline void async16(const uint4* g, uint4* l) {
  __builtin_amdgcn_global_load_lds(
      (const __attribute__((address_space(1))) unsigned int*)g,
      (__attribute__((address_space(3))) unsigned int*)l, 16, 0, 0);
}

// ---------------- prep: frag build (+ zero out/ws_l if atomic path) ----------
template <bool ZOUT>
__global__ __launch_bounds__(512) void attn_prep(const float* __restrict__ K,
                                                 const float* __restrict__ V,
                                                 float* __restrict__ out,
                                                 char* __restrict__ ws) {
  const int t = blockIdx.x * 512 + threadIdx.x;
  uint4* KVg = (uint4*)(ws + KV_OFF);
  if (t < 131072) {
    // K frag: lane holds K[key=lane&31][d0..d0+7], d0 = s*16 + (lane>>5)*8
    int kt = t >> 9, idx = t & 511;
    int lane = idx & 63, s = idx >> 6;
    int key = kt * 32 + (lane & 31);
    int d0  = s * 16 + (lane >> 5) * 8;
    const float4* src = (const float4*)(K + (size_t)key * D_K + d0);
    float4 a = src[0], b = src[1];
    float f[8] = {a.x, a.y, a.z, a.w, b.x, b.y, b.z, b.w};
    UH8 h;
    #pragma unroll
    for (int j = 0; j < 8; ++j) h.h[j] = (_Float16)f[j];
    KVg[(size_t)kt * 1024 + idx] = h.q;
  } else if (t < 262144) {
    // V frag: lane holds V[kb..kb+7][d], d = c*32 + (lane&31)
    int g = t - 131072;
    int kt = g >> 9, idx = g & 511;
    int lane = idx & 63, c = (idx >> 6) & 3, kstep = idx >> 8;
    int d  = c * 32 + (lane & 31);
    int kb = kt * 32 + kstep * 16 + (lane >> 5) * 8;
    UH8 h;
    #pragma unroll
    for (int j = 0; j < 8; ++j) h.h[j] = (_Float16)V[(size_t)(kb + j) * D_K + d];
    KVg[(size_t)kt * 1024 + 512 + idx] = h.q;
  } else if (ZOUT && t < 327680) {
    int i = t - 262144;  // zero out
    float4 z = make_float4(0.f, 0.f, 0.f, 0.f);
    float4* o4 = (float4*)out;
    #pragma unroll
    for (int j = 0; j < 4; ++j) o4[(size_t)i * 4 + j] = z;
  } else if (ZOUT && t < 329728) {
    int i = t - 327680;  // zero ws_l (first 8192 floats)
    ((float4*)(ws + WS_L_OFF))[i] = make_float4(0.f, 0.f, 0.f, 0.f);
  }
}

// ---------------- main attention kernel ----------------
// PARTIAL: 16 slices, fp16 partial stores, grid 512 (32 qb x 16), 2 w/SIMD.
// !PARTIAL: 8 slices, fp32 atomics into out, grid 256 (fallback).
template <bool PARTIAL>
__global__ __launch_bounds__(256, 2)
void attn_main(const float* __restrict__ Qg, float* __restrict__ out,
               char* __restrict__ ws) {
  constexpr int NSL   = PARTIAL ? 16 : 8;
  constexpr int ITERS = (S_LEN / NSL) / 32;

  __shared__ uint4 KV[2][1024];   // 32-key dbuf: [K 512 | V 512]

  const int tid   = threadIdx.x;
  const int wave  = tid >> 6;
  const int lane  = tid & 63;
  const int lrow  = lane & 31;
  const int lhalf = lane >> 5;

  const int blk = blockIdx.x;
  const int ks  = blk & (NSL - 1);       // k-slice; XCD = blk&7
  const int qb  = blk / NSL;
  const int qw  = qb * 256 + wave * 64;  // wave's 64-row q base (2 tiles)

  float* ws_l = (float*)(ws + WS_L_OFF);

  // ---- Q B-frags for both tiles: lane holds Q[q][d=(lane>>5)*8+j+16s] ----
  f16x8 qf0[8], qf1[8];
  {
    #pragma unroll
    for (int s = 0; s < 8; ++s) {
      const int d0 = s * 16 + lhalf * 8;
      const float4* s0 = (const float4*)(Qg + (size_t)(qw + lrow) * D_K + d0);
      const float4* s1 = (const float4*)(Qg + (size_t)(qw + 32 + lrow) * D_K + d0);
      float4 a0 = s0[0], b0 = s0[1], a1 = s1[0], b1 = s1[1];
      float f0[8] = {a0.x, a0.y, a0.z, a0.w, b0.x, b0.y, b0.z, b0.w};
      float f1[8] = {a1.x, a1.y, a1.z, a1.w, b1.x, b1.y, b1.z, b1.w};
      UH8 h0, h1;
      #pragma unroll
      for (int j = 0; j < 8; ++j) {
        h0.h[j] = (_Float16)(f0[j] * CSCALE);
        h1.h[j] = (_Float16)(f1[j] * CSCALE);
      }
      qf0[s] = h0.v;
      qf1[s] = h1.v;
    }
  }

  f32x16 O00{}, O01{}, O02{}, O03{};   // tile 0
  f32x16 O10{}, O11{}, O12{}, O13{};   // tile 1
  float lsum0 = 0.f, lsum1 = 0.f;

  const uint4* KVg = (const uint4*)(ws + KV_OFF);

  // prologue: stage tile 0
  {
    const size_t base = (size_t)(ks * ITERS) * 1024;
    #pragma unroll
    for (int i = 0; i < 4; ++i)
      async16(KVg + base + i * 256 + tid, &KV[0][i * 256 + tid]);
  }

  for (int it = 0; it < ITERS; ++it) {
    const int buf = it & 1;
    __syncthreads();   // drains async loads -> KV[buf] ready

    if (it + 1 < ITERS) {
      const size_t base = (size_t)(ks * ITERS + it + 1) * 1024;
      #pragma unroll
      for (int i = 0; i < 4; ++i)
        async16(KVg + base + i * 256 + tid, &KV[buf ^ 1][i * 256 + tid]);
    }

    // ---- S^T = K Q^T for BOTH tiles: each K frag feeds 2 MFMAs ----
    f32x16 S0{}, S1{};
    #pragma unroll
    for (int s = 0; s < 8; ++s) {
      f16x8 kf = __builtin_bit_cast(f16x8, KV[buf][s * 64 + lane]);
      S0 = __builtin_amdgcn_mfma_f32_32x32x16_f16(kf, qf0[s], S0, 0, 0, 0);
      S1 = __builtin_amdgcn_mfma_f32_32x32x16_f16(kf, qf1[s], S1, 0, 0, 0);
    }

    // ---- softmax both tiles -> A frags (in-register P transpose) ----
    UF4 A00, A01, A10, A11;
    {
      unsigned pk[8];
      #pragma unroll
      for (int i = 0; i < 8; ++i) {
        float p0 = __builtin_amdgcn_exp2f(S0[2 * i]);
        float p1 = __builtin_amdgcn_exp2f(S0[2 * i + 1]);
        lsum0 += p0 + p1;
        pk[i] = __builtin_bit_cast(unsigned, __builtin_amdgcn_cvt_pkrtz(p0, p1));
      }
      unsigned s0 = __shfl_xor(pk[0], 32), s1 = __shfl_xor(pk[1], 32);
      unsigned s2 = __shfl_xor(pk[2], 32), s3 = __shfl_xor(pk[3], 32);
      unsigned s4 = __shfl_xor(pk[4], 32), s5 = __shfl_xor(pk[5], 32);
      unsigned s6 = __shfl_xor(pk[6], 32), s7 = __shfl_xor(pk[7], 32);
      A00.u[0] = lhalf ? s2 : pk[0];
      A00.u[1] = lhalf ? s3 : pk[1];
      A00.u[2] = lhalf ? pk[2] : s0;
      A00.u[3] = lhalf ? pk[3] : s1;
      A01.u[0] = lhalf ? s6 : pk[4];
      A01.u[1] = lhalf ? s7 : pk[5];
      A01.u[2] = lhalf ? pk[6] : s4;
      A01.u[3] = lhalf ? pk[7] : s5;
    }
    {
      unsigned pk[8];
      #pragma unroll
      for (int i = 0; i < 8; ++i) {
        float p0 = __builtin_amdgcn_exp2f(S1[2 * i]);
        float p1 = __builtin_amdgcn_exp2f(S1[2 * i + 1]);
        lsum1 += p0 + p1;
        pk[i] = __builtin_bit_cast(unsigned, __builtin_amdgcn_cvt_pkrtz(p0, p1));
      }
      unsigned s0 = __shfl_xor(pk[0], 32), s1 = __shfl_xor(pk[1], 32);
      unsigned s2 = __shfl_xor(pk[2], 32), s3 = __shfl_xor(pk[3], 32);
      unsigned s4 = __shfl_xor(pk[4], 32), s5 = __shfl_xor(pk[5], 32);
      unsigned s6 = __shfl_xor(pk[6], 32), s7 = __shfl_xor(pk[7], 32);
      A10.u[0] = lhalf ? s2 : pk[0];
      A10.u[1] = lhalf ? s3 : pk[1];
      A10.u[2] = lhalf ? pk[2] : s0;
      A10.u[3] = lhalf ? pk[3] : s1;
      A11.u[0] = lhalf ? s6 : pk[4];
      A11.u[1] = lhalf ? s7 : pk[5];
      A11.u[2] = lhalf ? pk[6] : s4;
      A11.u[3] = lhalf ? pk[7] : s5;
    }

    // ---- O += P V for BOTH tiles: each V frag feeds 2 MFMAs ----
    #pragma unroll
    for (int kstep = 0; kstep < 2; ++kstep) {
      f16x8 p0 = kstep ? A01.v : A00.v;
      f16x8 p1 = kstep ? A11.v : A10.v;
      f16x8 v0 = __builtin_bit_cast(f16x8, KV[buf][512 + kstep * 256 +   0 + lane]);
      f16x8 v1 = __builtin_bit_cast(f16x8, KV[buf][512 + kstep * 256 +  64 + lane]);
      f16x8 v2 = __builtin_bit_cast(f16x8, KV[buf][512 + kstep * 256 + 128 + lane]);
      f16x8 v3 = __builtin_bit_cast(f16x8, KV[buf][512 + kstep * 256 + 192 + lane]);
      O00 = __builtin_amdgcn_mfma_f32_32x32x16_f16(p0, v0, O00, 0, 0, 0);
      O10 = __builtin_amdgcn_mfma_f32_32x32x16_f16(p1, v0, O10, 0, 0, 0);
      O01 = __builtin_amdgcn_mfma_f32_32x32x16_f16(p0, v1, O01, 0, 0, 0);
      O11 = __builtin_amdgcn_mfma_f32_32x32x16_f16(p1, v1, O11, 0, 0, 0);
      O02 = __builtin_amdgcn_mfma_f32_32x32x16_f16(p0, v2, O02, 0, 0, 0);
      O12 = __builtin_amdgcn_mfma_f32_32x32x16_f16(p1, v2, O12, 0, 0, 0);
      O03 = __builtin_amdgcn_mfma_f32_32x32x16_f16(p0, v3, O03, 0, 0, 0);
      O13 = __builtin_amdgcn_mfma_f32_32x32x16_f16(p1, v3, O13, 0, 0, 0);
    }
  }

  // ---- epilogue ----
  lsum0 += __shfl_xor(lsum0, 32);
  lsum1 += __shfl_xor(lsum1, 32);

  if (PARTIAL) {
    if (lhalf == 0) {
      ws_l[ks * S_LEN + qw + lrow]      = lsum0;
      ws_l[ks * S_LEN + qw + 32 + lrow] = lsum1;
    }
    // fp16 partial O: row of 64 uints; col c holds (d=c, d=c+64)
    unsigned* ob0 = (unsigned*)(ws + PART_OFF)
                  + (size_t)ks * S_LEN * 64 + (size_t)qw * 64;
    #pragma unroll
    for (int r = 0; r < 16; ++r) {
      int row = (r & 3) + 8 * (r >> 2) + 4 * lhalf;
      unsigned a02 = __builtin_bit_cast(unsigned, __builtin_amdgcn_cvt_pkrtz(O00[r], O02[r]));
      unsigned a13 = __builtin_bit_cast(unsigned, __builtin_amdgcn_cvt_pkrtz(O01[r], O03[r]));
      unsigned b02 = __builtin_bit_cast(unsigned, __builtin_amdgcn_cvt_pkrtz(O10[r], O12[r]));
      unsigned b13 = __builtin_bit_cast(unsigned, __builtin_amdgcn_cvt_pkrtz(O11[r], O13[r]));
      ob0[(size_t)row * 64 + lrow]             = a02;
      ob0[(size_t)row * 64 + 32 + lrow]        = a13;
      ob0[(size_t)(row + 32) * 64 + lrow]      = b02;
      ob0[(size_t)(row + 32) * 64 + 32 + lrow] = b13;
    }
  } else {
    if (lhalf == 0) {
      atomicAdd(ws_l + qw + lrow, lsum0);
      atomicAdd(ws_l + qw + 32 + lrow, lsum1);
    }
    #pragma unroll
    for (int r = 0; r < 16; ++r) {
      int row = (r & 3) + 8 * (r >> 2) + 4 * lhalf;
      float* d0 = out + (size_t)(qw + row) * D_K + lrow;
      atomicAdd(d0 +  0, O00[r]);
      atomicAdd(d0 + 32, O01[r]);
      atomicAdd(d0 + 64, O02[r]);
      atomicAdd(d0 + 96, O03[r]);
      float* d1 = out + (size_t)(qw + 32 + row) * D_K + lrow;
      atomicAdd(d1 +  0, O10[r]);
      atomicAdd(d1 + 32, O11[r]);
      atomicAdd(d1 + 64, O12[r]);
      atomicAdd(d1 + 96, O13[r]);
    }
  }
}

// ---------------- reduce 16 fp16 partials + normalize ----------------
__global__ __launch_bounds__(256) void attn_norm16(float* __restrict__ out,
                                                   const float* __restrict__ lpart,
                                                   const unsigned* __restrict__ opart) {
  int t = blockIdx.x * 256 + threadIdx.x;   // 131072 threads
  int q  = t >> 4;
  int cg = t & 15;                          // col group: cols 4cg..4cg+3

  float l = 0.f;
  #pragma unroll
  for (int s = 0; s < 16; ++s) l += lpart[s * S_LEN + q];
  float inv = 1.0f / l;

  float acc[8] = {0.f, 0.f, 0.f, 0.f, 0.f, 0.f, 0.f, 0.f};
  #pragma unroll
  for (int s = 0; s < 16; ++s) {
    const uint4* src = (const uint4*)(opart + (size_t)s * S_LEN * 64
                                      + (size_t)q * 64 + 4 * cg);
    uint4 u = src[0];
    UHP a, b, c, d;
    a.u = u.x; b.u = u.y; c.u = u.z; d.u = u.w;
    acc[0] += (float)a.h[0]; acc[4] += (float)a.h[1];
    acc[1] += (float)b.h[0]; acc[5] += (float)b.h[1];
    acc[2] += (float)c.h[0]; acc[6] += (float)c.h[1];
    acc[3] += (float)d.h[0]; acc[7] += (float)d.h[1];
  }
  float4* o4 = (float4*)out;
  o4[(size_t)q * 32 + cg] =
      make_float4(acc[0] * inv, acc[1] * inv, acc[2] * inv, acc[3] * inv);
  o4[(size_t)q * 32 + 16 + cg] =
      make_float4(acc[4] * inv, acc[5] * inv, acc[6] * inv, acc[7] * inv);
}

// ---------------- normalize only (atomic fallback) ----------------
__global__ __launch_bounds__(256) void attn_norm_fb(float* __restrict__ out,
                                                    const float* __restrict__ ws_l) {
  int i = blockIdx.x * 256 + threadIdx.x;
  float4* o4 = (float4*)out;
  float4 o = o4[i];
  float inv = 1.0f / ws_l[i >> 5];
  o.x *= inv; o.y *= inv; o.z *= inv; o.w *= inv;
  o4[i] = o;
}

extern "C" void kernel_launch(void* const* d_in, const int* in_sizes, int n_in,
                              void* d_out, int out_size, void* d_ws, size_t ws_size,
                              hipStream_t stream) {
  const float* q = (const float*)d_in[0];
  const float* k = (const float*)d_in[1];
  const float* v = (const float*)d_in[2];
  float* out = (float*)d_out;
  char* ws = (char*)d_ws;

  if (ws_size >= WS_NEED) {
    attn_prep<false><<<dim3(512), dim3(512), 0, stream>>>(k, v, out, ws);
    attn_main<true><<<dim3(512), dim3(256), 0, stream>>>(q, out, ws);
    attn_norm16<<<dim3(512), dim3(256), 0, stream>>>(
        out, (const float*)(ws + WS_L_OFF), (const unsigned*)(ws + PART_OFF));
  } else {
    attn_prep<true><<<dim3(645), dim3(512), 0, stream>>>(k, v, out, ws);
    attn_main<false><<<dim3(256), dim3(256), 0, stream>>>(q, out, ws);
    attn_norm_fb<<<dim3(1024), dim3(256), 0, stream>>>(
        out, (const float*)(ws + WS_L_OFF));
  }
}

// Round 16
// 114.041 us; speedup vs baseline: 1.1507x; 1.0232x over previous
//
#include <hip/hip_runtime.h>
#include <math.h>

// fp16-MFMA flash attention (no-max softmax), S=8192, D=128, fp32 in/out.
// R16 = R12 champion + ONE change: wave-parity subtile order. Barriers
// phase-lock all 4 waves (QK burst / softmax burst / PV burst together ->
// MfmaUtil 28 + VALUBusy 25 alternate, never overlap). Odd waves process the
// 64-key buffer's two 32-key subtiles in reverse order, so half the waves
// run MFMA while half run VALU at any instant.
// Core: transposed-S fp16 QK^T (A=K,B=Q), dual-S accumulators, in-register
// P transpose via shfl_xor(32), async global_load_lds 64-key dbuf, per-slice
// partial stores + reduce/norm. Graveyard: R8/R11 fusion, R9/R14 occupancy,
// R10 direct L2->reg, R13 source pipelining, R15 64q/wave.

typedef _Float16 f16x8 __attribute__((ext_vector_type(8)));
typedef float    f32x16 __attribute__((ext_vector_type(16)));

constexpr int S_LEN = 8192;
constexpr int D_K   = 128;
constexpr int NSLICE = 8;
constexpr int ITERS2 = (S_LEN / NSLICE) / 64;   // 16 iters of 64 keys

// ws: Lpart[8][8192] fp32 (256 KB) | KV frags (4 MB) | Opart[7] x 4 MB
constexpr size_t WS_L_OFF = 0;
constexpr size_t KV_OFF   = 262144;
constexpr size_t PART_OFF = KV_OFF + (size_t)256 * 16384;
constexpr size_t WS_NEED  = PART_OFF + (size_t)7 * S_LEN * D_K * 4;  // ~32.5 MB

#define CSCALE (0.08838834764831845f * 1.44269504088896340736f)

union UH8 { _Float16 h[8]; uint4 q; f16x8 v; };
union UF4 { unsigned u[4]; uint4 q; f16x8 v; };

__device__ inline void async16(const uint4* g, uint4* l) {
  __builtin_amdgcn_global_load_lds(
      (const __attribute__((address_space(1))) unsigned int*)g,
      (__attribute__((address_space(3))) unsigned int*)l, 16, 0, 0);
}

// ---------------- prep: frag build (+ zero out/ws_l if atomic path) ----------
template <bool ZOUT>
__global__ __launch_bounds__(512) void attn_prep(const float* __restrict__ K,
                                                 const float* __restrict__ V,
                                                 float* __restrict__ out,
                                                 char* __restrict__ ws) {
  const int t = blockIdx.x * 512 + threadIdx.x;
  uint4* KVg = (uint4*)(ws + KV_OFF);
  if (t < 131072) {
    // K frag: lane holds K[key=lane&31][d0..d0+7], d0 = s*16 + (lane>>5)*8
    int kt = t >> 9, idx = t & 511;
    int lane = idx & 63, s = idx >> 6;
    int key = kt * 32 + (lane & 31);
    int d0  = s * 16 + (lane >> 5) * 8;
    const float4* src = (const float4*)(K + (size_t)key * D_K + d0);
    float4 a = src[0], b = src[1];
    float f[8] = {a.x, a.y, a.z, a.w, b.x, b.y, b.z, b.w};
    UH8 h;
    #pragma unroll
    for (int j = 0; j < 8; ++j) h.h[j] = (_Float16)f[j];
    KVg[(size_t)kt * 1024 + idx] = h.q;
  } else if (t < 262144) {
    // V frag: lane holds V[kb..kb+7][d], d = c*32 + (lane&31)
    int g = t - 131072;
    int kt = g >> 9, idx = g & 511;
    int lane = idx & 63, c = (idx >> 6) & 3, kstep = idx >> 8;
    int d  = c * 32 + (lane & 31);
    int kb = kt * 32 + kstep * 16 + (lane >> 5) * 8;
    UH8 h;
    #pragma unroll
    for (int j = 0; j < 8; ++j) h.h[j] = (_Float16)V[(size_t)(kb + j) * D_K + d];
    KVg[(size_t)kt * 1024 + 512 + idx] = h.q;
  } else if (ZOUT && t < 327680) {
    int i = t - 262144;  // zero out: 65536 threads x 4 float4
    float4 z = make_float4(0.f, 0.f, 0.f, 0.f);
    float4* o4 = (float4*)out;
    #pragma unroll
    for (int j = 0; j < 4; ++j) o4[(size_t)i * 4 + j] = z;
  } else if (ZOUT && t < 329728) {
    int i = t - 327680;  // zero ws_l: 2048 float4
    ((float4*)(ws + WS_L_OFF))[i] = make_float4(0.f, 0.f, 0.f, 0.f);
  }
}

// ---------------- main attention kernel ----------------
template <bool PARTIAL>
__global__ __launch_bounds__(256, 2)
void attn_main(const float* __restrict__ Qg, float* __restrict__ out,
               char* __restrict__ ws) {
  __shared__ uint4 KV[2][2048];   // dbuf of 64-key pairs: [K|V][K|V]

  const int tid   = threadIdx.x;
  const int wave  = tid >> 6;
  const int lane  = tid & 63;
  const int lrow  = lane & 31;
  const int lhalf = lane >> 5;
  const int wpar  = wave & 1;     // wave parity -> subtile order swap

  const int blk = blockIdx.x;
  const int ks  = blk & 7;               // k-slice (XCD-pinned by dispatch % 8)
  const int qb  = blk >> 3;              // 0..63
  const int qw  = qb * 128 + wave * 32;  // wave's 32-row q base

  float* ws_l = (float*)(ws + WS_L_OFF);

  // ---- Q B-frags: lane holds Q[q=lane&31][d=(lane>>5)*8+j + 16s], scaled ----
  f16x8 qf[8];
  {
    const int q = qw + lrow;
    #pragma unroll
    for (int s = 0; s < 8; ++s) {
      const float4* src = (const float4*)(Qg + (size_t)q * D_K + s * 16 + lhalf * 8);
      float4 a = src[0], b = src[1];
      float f[8] = {a.x, a.y, a.z, a.w, b.x, b.y, b.z, b.w};
      UH8 h;
      #pragma unroll
      for (int j = 0; j < 8; ++j) h.h[j] = (_Float16)(f[j] * CSCALE);
      qf[s] = h.v;
    }
  }

  f32x16 O0{}, O1{}, O2{}, O3{};
  float lsum = 0.f;

  const uint4* KVg = (const uint4*)(ws + KV_OFF);

  // prologue: stage 64-key pair 0 (32 KB, 8 async16/thread)
  {
    const size_t base = (size_t)ks * 32768;
    #pragma unroll
    for (int i = 0; i < 8; ++i)
      async16(KVg + base + i * 256 + tid, &KV[0][i * 256 + tid]);
  }

  for (int it = 0; it < ITERS2; ++it) {
    const int buf = it & 1;
    __syncthreads();   // drains async loads -> KV[buf] ready

    if (it + 1 < ITERS2) {
      const size_t base = (size_t)ks * 32768 + (size_t)(it + 1) * 2048;
      #pragma unroll
      for (int i = 0; i < 8; ++i)
        async16(KVg + base + i * 256 + tid, &KV[buf ^ 1][i * 256 + tid]);
    }

    #pragma unroll
    for (int u = 0; u < 2; ++u) {
      // wave-parity de-phasing: odd waves take the subtiles in reverse order,
      // so their MFMA bursts overlap even waves' softmax VALU bursts.
      const int uu = u ^ wpar;
      const uint4* sub = &KV[buf][uu * 1024];

      // ---- S^T = K Q^T : dual accumulators, two interleaved 4-deep chains ----
      f32x16 Sa{}, Sb{};
      #pragma unroll
      for (int s = 0; s < 4; ++s) {
        f16x8 ka = __builtin_bit_cast(f16x8, sub[(2 * s    ) * 64 + lane]);
        f16x8 kb = __builtin_bit_cast(f16x8, sub[(2 * s + 1) * 64 + lane]);
        Sa = __builtin_amdgcn_mfma_f32_32x32x16_f16(ka, qf[2 * s    ], Sa, 0, 0, 0);
        Sb = __builtin_amdgcn_mfma_f32_32x32x16_f16(kb, qf[2 * s + 1], Sb, 0, 0, 0);
      }

      // ---- P^T = exp2(Sa+Sb); per-lane row sums; pack to fp16 pairs ----
      unsigned pk[8];
      #pragma unroll
      for (int i = 0; i < 8; ++i) {
        float p0 = __builtin_amdgcn_exp2f(Sa[2 * i]     + Sb[2 * i]);
        float p1 = __builtin_amdgcn_exp2f(Sa[2 * i + 1] + Sb[2 * i + 1]);
        lsum += p0 + p1;
        pk[i] = __builtin_bit_cast(unsigned, __builtin_amdgcn_cvt_pkrtz(p0, p1));
      }

      // ---- in-register transpose to P A-frags (lane<->lane+32 half swap) ----
      unsigned s0 = __shfl_xor(pk[0], 32), s1 = __shfl_xor(pk[1], 32);
      unsigned s2 = __shfl_xor(pk[2], 32), s3 = __shfl_xor(pk[3], 32);
      unsigned s4 = __shfl_xor(pk[4], 32), s5 = __shfl_xor(pk[5], 32);
      unsigned s6 = __shfl_xor(pk[6], 32), s7 = __shfl_xor(pk[7], 32);
      UF4 A0, A1;
      A0.u[0] = lhalf ? s2 : pk[0];
      A0.u[1] = lhalf ? s3 : pk[1];
      A0.u[2] = lhalf ? pk[2] : s0;
      A0.u[3] = lhalf ? pk[3] : s1;
      A1.u[0] = lhalf ? s6 : pk[4];
      A1.u[1] = lhalf ? s7 : pk[5];
      A1.u[2] = lhalf ? pk[6] : s4;
      A1.u[3] = lhalf ? pk[7] : s5;

      // ---- O += P V : 8 MFMAs, 4 independent chains ----
      #pragma unroll
      for (int kstep = 0; kstep < 2; ++kstep) {
        f16x8 pf = kstep ? A1.v : A0.v;
        f16x8 v0 = __builtin_bit_cast(f16x8, sub[512 + kstep * 256 +   0 + lane]);
        f16x8 v1 = __builtin_bit_cast(f16x8, sub[512 + kstep * 256 +  64 + lane]);
        f16x8 v2 = __builtin_bit_cast(f16x8, sub[512 + kstep * 256 + 128 + lane]);
        f16x8 v3 = __builtin_bit_cast(f16x8, sub[512 + kstep * 256 + 192 + lane]);
        O0 = __builtin_amdgcn_mfma_f32_32x32x16_f16(pf, v0, O0, 0, 0, 0);
        O1 = __builtin_amdgcn_mfma_f32_32x32x16_f16(pf, v1, O1, 0, 0, 0);
        O2 = __builtin_amdgcn_mfma_f32_32x32x16_f16(pf, v2, O2, 0, 0, 0);
        O3 = __builtin_amdgcn_mfma_f32_32x32x16_f16(pf, v3, O3, 0, 0, 0);
      }
    }
  }

  // ---- epilogue ----
  lsum += __shfl_xor(lsum, 32);           // combine the two key-halves

  if (PARTIAL) {
    if (lhalf == 0) ws_l[ks * S_LEN + qw + lrow] = lsum;   // plain store
    float* obase = (ks == 0) ? out
                 : (float*)(ws + PART_OFF) + (size_t)(ks - 1) * S_LEN * D_K;
    #pragma unroll
    for (int r = 0; r < 16; ++r) {
      int row = (r & 3) + 8 * (r >> 2) + 4 * lhalf;
      float* dst = obase + (size_t)(qw + row) * D_K + lrow;
      dst[ 0] = O0[r];
      dst[32] = O1[r];
      dst[64] = O2[r];
      dst[96] = O3[r];
    }
  } else {
    if (lhalf == 0) atomicAdd(ws_l + qw + lrow, lsum);
    #pragma unroll
    for (int r = 0; r < 16; ++r) {
      int row = (r & 3) + 8 * (r >> 2) + 4 * lhalf;
      float* dst = out + (size_t)(qw + row) * D_K + lrow;
      atomicAdd(dst +  0, O0[r]);
      atomicAdd(dst + 32, O1[r]);
      atomicAdd(dst + 64, O2[r]);
      atomicAdd(dst + 96, O3[r]);
    }
  }
}

// ---------------- reduce partials (nparts>0) or just normalize (nparts=0) ----
__global__ __launch_bounds__(256) void attn_norm(float* __restrict__ out,
                                                 const float* __restrict__ lpart,
                                                 const float* __restrict__ opart,
                                                 int nparts) {
  int i = blockIdx.x * 256 + threadIdx.x;  // float4 index, 262144 total
  int q = i >> 5;
  float4* o4 = (float4*)out;
  float4 acc = o4[i];
  float l = lpart[q];
  for (int s = 1; s <= nparts; ++s) {
    float4 p = ((const float4*)opart)[(size_t)(s - 1) * 262144 + i];
    acc.x += p.x; acc.y += p.y; acc.z += p.z; acc.w += p.w;
    l += lpart[s * S_LEN + q];
  }
  float inv = 1.0f / l;
  acc.x *= inv; acc.y *= inv; acc.z *= inv; acc.w *= inv;
  o4[i] = acc;
}

extern "C" void kernel_launch(void* const* d_in, const int* in_sizes, int n_in,
                              void* d_out, int out_size, void* d_ws, size_t ws_size,
                              hipStream_t stream) {
  const float* q = (const float*)d_in[0];
  const float* k = (const float*)d_in[1];
  const float* v = (const float*)d_in[2];
  float* out = (float*)d_out;
  char* ws = (char*)d_ws;

  if (ws_size >= WS_NEED) {
    attn_prep<false><<<dim3(512), dim3(512), 0, stream>>>(k, v, out, ws);
    attn_main<true><<<dim3(512), dim3(256), 0, stream>>>(q, out, ws);
    attn_norm<<<dim3(1024), dim3(256), 0, stream>>>(
        out, (const float*)(ws + WS_L_OFF), (const float*)(ws + PART_OFF), 7);
  } else {
    attn_prep<true><<<dim3(645), dim3(512), 0, stream>>>(k, v, out, ws);
    attn_main<false><<<dim3(512), dim3(256), 0, stream>>>(q, out, ws);
    attn_norm<<<dim3(1024), dim3(256), 0, stream>>>(
        out, (const float*)(ws + WS_L_OFF), (const float*)(ws + PART_OFF), 0);
  }
}